// Round 1
// baseline (212.646 us; speedup 1.0000x reference)
//
#include <hip/hip_runtime.h>
#include <hip/hip_bf16.h>
#include <math.h>

// Problem constants (B=1024, V=2, M=C=256)
// S[c0,c1] = sum_kk (w[kk>>8]*W0[kk,c0]) * W1[kk,c1],  kk = k*256+m in [0,65536)
// out[b] = log(S[x0[b], x1[b]])

#define NC       256
#define KKTOT    65536
#define SPLITS   128
#define KCHUNK   512          // KKTOT / SPLITS
#define BK       32
#define LDS_STRIDE 40         // shorts per c-row: 32 + 8 pad -> 80 B (multiple of 16 B)

typedef float  f32x4  __attribute__((ext_vector_type(4)));
typedef short  bf16x8 __attribute__((ext_vector_type(8)));

static __device__ __forceinline__ short f2bf(float f) {
    // round-to-nearest-even fp32 -> bf16 (inputs are positive probabilities; no NaN/Inf)
    unsigned u = __builtin_bit_cast(unsigned, f);
    u += 0x7fffu + ((u >> 16) & 1u);
    return (short)(u >> 16);
}

// USE_PART: write per-block partial tiles to P (deterministic, needs 33.5 MB ws)
// else:     atomicAdd into S (256 KB ws, pre-zeroed)
template <bool USE_PART>
__global__ __launch_bounds__(256, 2) void gemm_s_kernel(
    const float* __restrict__ W, const float* __restrict__ wsum,
    float* __restrict__ out_acc)
{
    __shared__ short As[128 * LDS_STRIDE];
    __shared__ short Bs[128 * LDS_STRIDE];

    const int tile   = blockIdx.x;            // 0..3 : (c0 half, c1 half)
    const int split  = blockIdx.y;            // 0..SPLITS-1
    const int c0base = (tile >> 1) * 128;
    const int c1base = (tile & 1) * 128;
    const long kbase = (long)split * KCHUNK;

    const float* __restrict__ Ag = W;               // W0 flat [65536][256]
    const float* __restrict__ Bg = W + 16777216;    // W1 flat

    const int t  = threadIdx.x;
    const int cq = t & 31;     // stages columns c = cq*4 .. cq*4+3
    const int kq = t >> 5;     // stages rows    kk = kq*4 .. kq*4+3 (of BK=32)

    const int lane = t & 63;
    const int wv   = t >> 6;             // wave 0..3
    const int wc0  = (wv >> 1) * 64;     // wave tile origin within 128x128
    const int wc1  = (wv & 1) * 64;
    const int ml   = lane & 15;
    const int qd   = lane >> 4;

    f32x4 acc[4][4];
#pragma unroll
    for (int i = 0; i < 4; ++i)
#pragma unroll
        for (int j = 0; j < 4; ++j) acc[i][j] = (f32x4){0.f, 0.f, 0.f, 0.f};

    for (int it = 0; it < KCHUNK / BK; ++it) {
        const long k0 = kbase + (long)it * BK;
        float4 a4[4], b4[4];
        float  wsc[4];
#pragma unroll
        for (int r = 0; r < 4; ++r) {
            const long kk = k0 + kq * 4 + r;
            wsc[r] = wsum[kk >> 8];
            a4[r]  = *(const float4*)(Ag + kk * 256 + (c0base + cq * 4));
            b4[r]  = *(const float4*)(Bg + kk * 256 + (c1base + cq * 4));
        }
        __syncthreads();   // previous iteration's fragment reads complete
        const float* af32 = reinterpret_cast<const float*>(a4);
        const float* bf32 = reinterpret_cast<const float*>(b4);
#pragma unroll
        for (int j = 0; j < 4; ++j) {
            short4 av, bv;
            av.x = f2bf(af32[0 * 4 + j] * wsc[0]);
            av.y = f2bf(af32[1 * 4 + j] * wsc[1]);
            av.z = f2bf(af32[2 * 4 + j] * wsc[2]);
            av.w = f2bf(af32[3 * 4 + j] * wsc[3]);
            bv.x = f2bf(bf32[0 * 4 + j]);
            bv.y = f2bf(bf32[1 * 4 + j]);
            bv.z = f2bf(bf32[2 * 4 + j]);
            bv.w = f2bf(bf32[3 * 4 + j]);
            const int c = cq * 4 + j;
            *(short4*)&As[c * LDS_STRIDE + kq * 4] = av;   // byte addr c*80 + kq*8 (8B aligned)
            *(short4*)&Bs[c * LDS_STRIDE + kq * 4] = bv;
        }
        __syncthreads();
        // fragments: lane holds elem [c = base + (lane&15)][kk = (lane>>4)*8 + j]
        bf16x8 af[4], bf[4];
#pragma unroll
        for (int mi = 0; mi < 4; ++mi)
            af[mi] = *(const bf16x8*)&As[(wc0 + mi * 16 + ml) * LDS_STRIDE + qd * 8];
#pragma unroll
        for (int ni = 0; ni < 4; ++ni)
            bf[ni] = *(const bf16x8*)&Bs[(wc1 + ni * 16 + ml) * LDS_STRIDE + qd * 8];
#pragma unroll
        for (int mi = 0; mi < 4; ++mi)
#pragma unroll
            for (int ni = 0; ni < 4; ++ni)
                acc[mi][ni] = __builtin_amdgcn_mfma_f32_16x16x32_bf16(
                    af[mi], bf[ni], acc[mi][ni], 0, 0, 0);
    }

    // Epilogue. C/D layout (verified): col = lane&15, row = (lane>>4)*4 + reg
    if (USE_PART) {
        float* __restrict__ Pb = out_acc + ((size_t)split * 4 + tile) * 16384;
#pragma unroll
        for (int mi = 0; mi < 4; ++mi) {
            const int row0 = wc0 + mi * 16 + qd * 4;
#pragma unroll
            for (int ni = 0; ni < 4; ++ni) {
                const int col = wc1 + ni * 16 + ml;
#pragma unroll
                for (int r = 0; r < 4; ++r)
                    Pb[(row0 + r) * 128 + col] = acc[mi][ni][r];
            }
        }
    } else {
#pragma unroll
        for (int mi = 0; mi < 4; ++mi) {
            const int row0 = c0base + wc0 + mi * 16 + qd * 4;
#pragma unroll
            for (int ni = 0; ni < 4; ++ni) {
                const int col = c1base + wc1 + ni * 16 + ml;
#pragma unroll
                for (int r = 0; r < 4; ++r)
                    atomicAdd(&out_acc[(row0 + r) * 256 + col], acc[mi][ni][r]);
            }
        }
    }
}

// Partials path: one block (1 wave) per b; lanes sum the 128 split partials.
__global__ __launch_bounds__(64) void finish_part_kernel(
    const int* __restrict__ x, const float* __restrict__ P, float* __restrict__ out)
{
    const int b  = blockIdx.x;
    const int t  = threadIdx.x;        // 0..63
    const int x0 = x[2 * b], x1 = x[2 * b + 1];
    const int tile  = ((x0 >> 7) << 1) | (x1 >> 7);
    const int local = ((x0 & 127) << 7) | (x1 & 127);
    float v = P[((size_t)(t) * 4 + tile) * 16384 + local]
            + P[((size_t)(t + 64) * 4 + tile) * 16384 + local];
#pragma unroll
    for (int off = 32; off > 0; off >>= 1) v += __shfl_down(v, off);
    if (t == 0) out[b] = logf(v);
}

// Atomic path: S is fully reduced already.
__global__ __launch_bounds__(64) void finish_atom_kernel(
    const int* __restrict__ x, const float* __restrict__ S, float* __restrict__ out)
{
    const int b = blockIdx.x * 64 + threadIdx.x;   // grid 16 x 64 = 1024
    const int x0 = x[2 * b], x1 = x[2 * b + 1];
    out[b] = logf(S[x0 * 256 + x1]);
}

extern "C" void kernel_launch(void* const* d_in, const int* in_sizes, int n_in,
                              void* d_out, int out_size, void* d_ws, size_t ws_size,
                              hipStream_t stream)
{
    const int*   x    = (const int*)d_in[0];     // [1024,2] int32
    const float* W    = (const float*)d_in[1];   // [2,256,256,256] fp32
    const float* wsum = (const float*)d_in[2];   // [256] fp32
    float* out = (float*)d_out;                  // [1024] fp32

    const size_t part_bytes = (size_t)SPLITS * 4 * 16384 * sizeof(float); // 33.5 MB

    if (ws_size >= part_bytes) {
        float* P = (float*)d_ws;
        gemm_s_kernel<true><<<dim3(4, SPLITS), 256, 0, stream>>>(W, wsum, P);
        finish_part_kernel<<<dim3(1024), 64, 0, stream>>>(x, P, out);
    } else {
        float* S = (float*)d_ws;                 // 256 KB
        hipMemsetAsync(d_ws, 0, 65536 * sizeof(float), stream);
        gemm_s_kernel<false><<<dim3(4, SPLITS), 256, 0, stream>>>(W, wsum, S);
        finish_atom_kernel<<<dim3(16), 64, 0, stream>>>(x, S, out);
    }
}

// Round 2
// 208.924 us; speedup vs baseline: 1.0178x; 1.0178x over previous
//
#include <hip/hip_runtime.h>
#include <math.h>

// S[c0,c1] = sum_kk (w[kk>>8]*W0[kk,c0]) * W1[kk,c1],  kk in [0,65536)
// out[b] = log(S[x0[b], x1[b]])
//
// gemm: grid (2 c1-tiles, 128 splits), 512 threads (8 waves, 4x2 wave grid of
// 64x64), tile = 256(c0) x 128(c1), KCHUNK=512 (exactly 2 latent k per block
// -> w_sum scale is wave-uniform per iteration). Partials P[split][c1tile]
// ride L2/L3; finish gathers 256 partials per b and takes the log.

#define SPLITS  128
#define KCHUNK  512
#define BK      32
#define NITER   (KCHUNK / BK)   // 16
#define LDSS    40              // shorts per c-row: 32 k + 8 pad = 80 B

typedef float  f32x4  __attribute__((ext_vector_type(4)));
typedef short  bf16x8 __attribute__((ext_vector_type(8)));

static __device__ __forceinline__ short f2bf(float f) {
    // RNE fp32 -> bf16 (inputs are positive probabilities; no NaN/Inf)
    unsigned u = __builtin_bit_cast(unsigned, f);
    u += 0x7fffu + ((u >> 16) & 1u);
    return (short)(u >> 16);
}

template <bool USE_PART>
__global__ __launch_bounds__(512, 2) void gemm_s_kernel(
    const float* __restrict__ W, const float* __restrict__ wsum,
    float* __restrict__ out_acc)
{
    __shared__ short As[256 * LDSS];   // [c0][k]
    __shared__ short Bs[128 * LDSS];   // [c1][k]

    const int  c1tile = blockIdx.x;            // 0..1
    const int  split  = blockIdx.y;            // 0..127
    const long kbase  = (long)split * KCHUNK;

    const float* __restrict__ Ag = W;                                  // W0 [65536][256]
    const float* __restrict__ Bg = W + 16777216 + (long)c1tile * 128;  // W1 + col offset

    const int t = threadIdx.x;
    // A staging: 64 c-quads x 8 k-rows, r=0..3  (4 float4 / thread)
    const int cqA = (t & 63) * 4;
    const int kqA = (t >> 6) * 4;
    // B staging: 32 c-quads x 16 k-rows, r=0..1 (2 float4 / thread)
    const int cqB = (t & 31) * 4;
    const int kqB = (t >> 5) * 2;

    const int lane = t & 63;
    const int wv   = t >> 6;             // wave 0..7
    const int wc0  = (wv & 3) * 64;      // 4 wave-tiles along c0 (256)
    const int wc1  = (wv >> 2) * 64;     // 2 along c1 (128)
    const int ml   = lane & 15;
    const int qd   = lane >> 4;

    const float w0 = wsum[split * 2];
    const float w1 = wsum[split * 2 + 1];

    f32x4 acc[4][4];
#pragma unroll
    for (int i = 0; i < 4; ++i)
#pragma unroll
        for (int j = 0; j < 4; ++j) acc[i][j] = (f32x4){0.f, 0.f, 0.f, 0.f};

    for (int it = 0; it < NITER; ++it) {
        const long  k0 = kbase + (long)it * BK;
        const float wk = (it < NITER / 2) ? w0 : w1;   // wave-uniform
        float4 a4[4], b4[2];
#pragma unroll
        for (int r = 0; r < 4; ++r)
            a4[r] = *(const float4*)(Ag + (k0 + kqA + r) * 256 + cqA);
#pragma unroll
        for (int r = 0; r < 2; ++r)
            b4[r] = *(const float4*)(Bg + (k0 + kqB + r) * 256 + cqB);
        __syncthreads();   // previous iteration's fragment reads complete
        const float* af32 = reinterpret_cast<const float*>(a4);
        const float* bf32 = reinterpret_cast<const float*>(b4);
#pragma unroll
        for (int j = 0; j < 4; ++j) {
            short4 av;
            av.x = f2bf(af32[0 * 4 + j] * wk);
            av.y = f2bf(af32[1 * 4 + j] * wk);
            av.z = f2bf(af32[2 * 4 + j] * wk);
            av.w = f2bf(af32[3 * 4 + j] * wk);
            *(short4*)&As[(cqA + j) * LDSS + kqA] = av;   // 8 B aligned
            short2 bv;
            bv.x = f2bf(bf32[0 * 4 + j]);
            bv.y = f2bf(bf32[1 * 4 + j]);
            *(short2*)&Bs[(cqB + j) * LDSS + kqB] = bv;   // 4 B aligned
        }
        __syncthreads();
        // fragment: lane holds A[c = base+(lane&15)][k = (lane>>4)*8 + j]
        bf16x8 afr[4];
#pragma unroll
        for (int mi = 0; mi < 4; ++mi)
            afr[mi] = *(const bf16x8*)&As[(wc0 + mi * 16 + ml) * LDSS + qd * 8];
#pragma unroll
        for (int ni = 0; ni < 4; ++ni) {
            const bf16x8 bfr = *(const bf16x8*)&Bs[(wc1 + ni * 16 + ml) * LDSS + qd * 8];
#pragma unroll
            for (int mi = 0; mi < 4; ++mi)
                acc[mi][ni] = __builtin_amdgcn_mfma_f32_16x16x32_bf16(
                    afr[mi], bfr, acc[mi][ni], 0, 0, 0);
        }
    }

    // Epilogue. C/D layout: col = lane&15, row = (lane>>4)*4 + reg
    if (USE_PART) {
        float* __restrict__ Pb = out_acc + ((size_t)split * 2 + c1tile) * 32768;
#pragma unroll
        for (int mi = 0; mi < 4; ++mi) {
            const int row0 = wc0 + mi * 16 + qd * 4;
#pragma unroll
            for (int ni = 0; ni < 4; ++ni) {
                const int col = wc1 + ni * 16 + ml;
#pragma unroll
                for (int r = 0; r < 4; ++r)
                    Pb[(row0 + r) * 128 + col] = acc[mi][ni][r];
            }
        }
    } else {
#pragma unroll
        for (int mi = 0; mi < 4; ++mi) {
            const int row0 = wc0 + mi * 16 + qd * 4;   // c0 is global already
#pragma unroll
            for (int ni = 0; ni < 4; ++ni) {
                const int col = c1tile * 128 + wc1 + ni * 16 + ml;
#pragma unroll
                for (int r = 0; r < 4; ++r)
                    atomicAdd(&out_acc[(row0 + r) * 256 + col], acc[mi][ni][r]);
            }
        }
    }
}

// One wave per b: lanes sum the 128 split partials (2 each), shuffle-reduce, log.
__global__ __launch_bounds__(64) void finish_part_kernel(
    const int* __restrict__ x, const float* __restrict__ P, float* __restrict__ out)
{
    const int b  = blockIdx.x;
    const int t  = threadIdx.x;        // 0..63
    const int x0 = x[2 * b], x1 = x[2 * b + 1];
    const int t1 = x1 >> 7;
    const size_t base = (size_t)x0 * 128 + (x1 & 127);
    float v = P[((size_t)t * 2 + t1) * 32768 + base]
            + P[((size_t)(t + 64) * 2 + t1) * 32768 + base];
#pragma unroll
    for (int off = 32; off > 0; off >>= 1) v += __shfl_down(v, off);
    if (t == 0) out[b] = logf(v);
}

__global__ __launch_bounds__(64) void finish_atom_kernel(
    const int* __restrict__ x, const float* __restrict__ S, float* __restrict__ out)
{
    const int b  = blockIdx.x * 64 + threadIdx.x;   // 16 x 64 = 1024
    const int x0 = x[2 * b], x1 = x[2 * b + 1];
    out[b] = logf(S[x0 * 256 + x1]);
}

extern "C" void kernel_launch(void* const* d_in, const int* in_sizes, int n_in,
                              void* d_out, int out_size, void* d_ws, size_t ws_size,
                              hipStream_t stream)
{
    const int*   x    = (const int*)d_in[0];     // [1024,2] int32
    const float* W    = (const float*)d_in[1];   // [2,256,256,256] fp32
    const float* wsum = (const float*)d_in[2];   // [256] fp32
    float* out = (float*)d_out;                  // [1024] fp32

    const size_t part_bytes = (size_t)SPLITS * 2 * 32768 * sizeof(float); // 33.5 MB

    if (ws_size >= part_bytes) {
        float* P = (float*)d_ws;
        gemm_s_kernel<true><<<dim3(2, SPLITS), 512, 0, stream>>>(W, wsum, P);
        finish_part_kernel<<<dim3(1024), 64, 0, stream>>>(x, P, out);
    } else {
        float* S = (float*)d_ws;                 // 256 KB, must be zeroed
        hipMemsetAsync(d_ws, 0, 65536 * sizeof(float), stream);
        gemm_s_kernel<false><<<dim3(2, SPLITS), 512, 0, stream>>>(W, wsum, S);
        finish_atom_kernel<<<dim3(16), 64, 0, stream>>>(x, S, out);
    }
}